// Round 15
// baseline (135.587 us; speedup 1.0000x reference)
//
#include <hip/hip_runtime.h>
#include <hip/hip_fp16.h>
#include <math.h>

#define N_NODES 50000
#define N_EDGES 1600000
#define ET (N_EDGES + N_NODES)
#define F_OUT 64
#define F_IN 128
#define SLOPE 0.2f
#define BSHIFT 5                               // 32 nodes per bucket
#define BNODES 32
#define NBUCK ((N_NODES + BNODES - 1) >> BSHIFT)   // 1563 buckets
#define CAP 1344                               // mean 1056 + 8.9 sigma
#define EPB 1024                               // edges per partition block
#define PBLOCKS ((ET + EPB - 1) / EPB)         // 1612

typedef _Float16 half8 __attribute__((ext_vector_type(8)));
typedef _Float16 half4 __attribute__((ext_vector_type(4)));
typedef float f32x4 __attribute__((ext_vector_type(4)));

// ---------------- MFMA GEMM: xp(f16) = x @ W + attention logits (+bcur zero) ----------------
__global__ __launch_bounds__(256) void gemm_kernel(const float4* __restrict__ x4,
                                                   const float* __restrict__ W,
                                                   const float* __restrict__ a_src,
                                                   const float* __restrict__ a_dst,
                                                   _Float16* __restrict__ xph,
                                                   float* __restrict__ alpha_s,
                                                   float* __restrict__ alpha_d,
                                                   int* __restrict__ bcur) {
    __shared__ _Float16 xs[64][136];          // padded: row stride 272B
    int t = threadIdx.x;
    if (blockIdx.x == 0)
        for (int i = t; i < NBUCK; i += 256) bcur[i] = 0;
    int wave = t >> 6, lane = t & 63;
    int g = lane >> 4, c16 = lane & 15;

    size_t rbase = (size_t)blockIdx.x * 64;
#pragma unroll
    for (int i = 0; i < 8; ++i) {
        int idx = t + i * 256;                 // over 64*32 float4
        int row = idx >> 5, c4 = idx & 31;
        size_t gr = rbase + row;
        if (gr >= N_NODES) gr = N_NODES - 1;
        float4 v = x4[gr * (F_IN / 4) + c4];
        half4 hv = { (_Float16)v.x, (_Float16)v.y, (_Float16)v.z, (_Float16)v.w };
        *(half4*)&xs[row][c4 * 4] = hv;
    }

    // B fragments straight from global W (L2-resident 32 KB)
    half8 bw[4][4];
#pragma unroll
    for (int nt = 0; nt < 4; ++nt)
#pragma unroll
        for (int kt = 0; kt < 4; ++kt) {
            int col = nt * 16 + c16;
            int k0 = kt * 32 + g * 8;
#pragma unroll
            for (int e = 0; e < 8; ++e)
                bw[nt][kt][e] = (_Float16)W[(k0 + e) * F_OUT + col];
        }
    __syncthreads();

    int r0 = wave * 16;
    half8 af[4];
#pragma unroll
    for (int kt = 0; kt < 4; ++kt)
        af[kt] = *(const half8*)&xs[r0 + c16][kt * 32 + g * 8];

    f32x4 acc[4];
#pragma unroll
    for (int nt = 0; nt < 4; ++nt) {
        acc[nt] = (f32x4){0.f, 0.f, 0.f, 0.f};
#pragma unroll
        for (int kt = 0; kt < 4; ++kt)
            acc[nt] = __builtin_amdgcn_mfma_f32_16x16x32_f16(af[kt], bw[nt][kt], acc[nt], 0, 0, 0);
    }

    int growbase = (int)rbase + r0 + g * 4;
#pragma unroll
    for (int nt = 0; nt < 4; ++nt) {
#pragma unroll
        for (int r = 0; r < 4; ++r) {
            int row = growbase + r;
            if (row < N_NODES)
                xph[(size_t)row * F_OUT + nt * 16 + c16] = (_Float16)acc[nt][r];
        }
    }
    float asl[4], adl[4];
#pragma unroll
    for (int nt = 0; nt < 4; ++nt) {
        asl[nt] = a_src[nt * 16 + c16];
        adl[nt] = a_dst[nt * 16 + c16];
    }
#pragma unroll
    for (int r = 0; r < 4; ++r) {
        float ps = 0.f, pd = 0.f;
#pragma unroll
        for (int nt = 0; nt < 4; ++nt) {
            ps = fmaf(acc[nt][r], asl[nt], ps);
            pd = fmaf(acc[nt][r], adl[nt], pd);
        }
#pragma unroll
        for (int off = 1; off < 16; off <<= 1) {
            ps += __shfl_xor(ps, off);
            pd += __shfl_xor(pd, off);
        }
        int row = growbase + r;
        if (c16 == 0 && row < N_NODES) { alpha_s[row] = ps; alpha_d[row] = pd; }
    }
}

// ---------------- partition: single-pass rank capture, 4 edges/thread, 1612 blocks ----------------
__global__ __launch_bounds__(256) void part_kernel(const int* __restrict__ ei,
                                                   int* __restrict__ bcur,
                                                   unsigned* __restrict__ rec) {
    __shared__ int lc[NBUCK];                 // 6.3 KB
    __shared__ int lbase[NBUCK];              // 6.3 KB
    int t = threadIdx.x;
    for (int b = t; b < NBUCK; b += 256) lc[b] = 0;
    __syncthreads();

    int e = blockIdx.x * EPB + t * 4;
    int4 sv, dv;
    if (e + 3 < N_EDGES) {                     // fast path: 16B aligned vector loads
        sv = *(const int4*)&ei[e];
        dv = *(const int4*)&ei[N_EDGES + e];
    } else {
        int* sp = (int*)&sv; int* dp = (int*)&dv;
#pragma unroll
        for (int j = 0; j < 4; ++j) {
            int ee = e + j;
            if (ee < N_EDGES)      { sp[j] = ei[ee]; dp[j] = ei[N_EDGES + ee]; }
            else if (ee < ET)      { sp[j] = dp[j] = ee - N_EDGES; }
            else                   { sp[j] = dp[j] = -1; }
        }
    }
    const int* sp = (const int*)&sv; const int* dp = (const int*)&dv;
    unsigned u[4]; short bk[4]; unsigned short rk[4];
#pragma unroll
    for (int j = 0; j < 4; ++j) {
        int d = dp[j];
        if (d >= 0) {
            int b = d >> BSHIFT;
            bk[j] = (short)b;
            rk[j] = (unsigned short)atomicAdd(&lc[b], 1);
            u[j] = (unsigned)sp[j] | ((unsigned)d << 16);
        } else bk[j] = -1;
    }
    __syncthreads();
    for (int b = t; b < NBUCK; b += 256)
        if (lc[b]) lbase[b] = b * CAP + atomicAdd(&bcur[b], lc[b]);
    __syncthreads();
#pragma unroll
    for (int j = 0; j < 4; ++j)
        if (bk[j] >= 0) rec[lbase[bk[j]] + rk[j]] = u[j];
}

// ---------------- per-bucket CSR build + edge-weight precompute (32-node buckets) ----------------
__global__ __launch_bounds__(256) void csrb_kernel(const unsigned* __restrict__ rec,
                                                   const int* __restrict__ bcur,
                                                   const float* __restrict__ as,
                                                   const float* __restrict__ ad,
                                                   int* __restrict__ offsets,
                                                   int* __restrict__ counts,
                                                   unsigned* __restrict__ wcsr) {
    __shared__ unsigned lrec[CAP];            // 5.4 KB
    __shared__ int lcnt[BNODES], loff[BNODES], lcur[BNODES];
    __shared__ float adl[BNODES];
    int t = threadIdx.x;
    int b = blockIdx.x;
    int n0 = b << BSHIFT;
    int r0 = b * CAP;
    int cnt_b = bcur[b];
    if (t < BNODES) {
        lcnt[t] = 0; lcur[t] = 0;
        adl[t] = (n0 + t < N_NODES) ? ad[n0 + t] : 0.f;
    }
    __syncthreads();
    for (int i = t; i < cnt_b; i += 256) {
        unsigned u = rec[r0 + i];
        lrec[i] = u;
        atomicAdd(&lcnt[(u >> 16) & (BNODES - 1)], 1);
    }
    __syncthreads();
    if (t < BNODES) {                          // single-wave scan of 32 counters
        int v = lcnt[t];
        int incl = v;
#pragma unroll
        for (int off = 1; off < BNODES; off <<= 1) {
            int n = __shfl_up(incl, off);
            if (t >= off) incl += n;
        }
        loff[t] = incl - v;
        if (n0 + t < N_NODES) { counts[n0 + t] = v; offsets[n0 + t] = r0 + incl - v; }
    }
    __syncthreads();
    for (int i = t; i < cnt_b; i += 256) {
        unsigned u = lrec[i];
        int dl = (u >> 16) & (BNODES - 1);
        int s = u & 0xFFFFu;
        float ev = as[s] + adl[dl];
        ev = ev > 0.f ? ev : SLOPE * ev;
        float w = __expf(ev);
        int pos = atomicAdd(&lcur[dl], 1);
        wcsr[r0 + loff[dl] + pos] =
            (unsigned)s | ((unsigned)__half_as_ushort(__float2half(w)) << 16);
    }
}

// ---------------- gather: wave/dst, 8 edge-streams x 8 lanes, uint4 row loads ----------------
#define CONS(u_, h_)                                                           \
    {                                                                          \
        float w = __half2float(__ushort_as_half((unsigned short)((u_) >> 16)));\
        float2 p;                                                              \
        p = __half22float2(__builtin_bit_cast(__half2, (h_).x));               \
        a0 = fmaf(w, p.x, a0); a1 = fmaf(w, p.y, a1);                          \
        p = __half22float2(__builtin_bit_cast(__half2, (h_).y));               \
        a2 = fmaf(w, p.x, a2); a3 = fmaf(w, p.y, a3);                          \
        p = __half22float2(__builtin_bit_cast(__half2, (h_).z));               \
        a4 = fmaf(w, p.x, a4); a5 = fmaf(w, p.y, a5);                          \
        p = __half22float2(__builtin_bit_cast(__half2, (h_).w));               \
        a6 = fmaf(w, p.x, a6); a7 = fmaf(w, p.y, a7);                          \
        ws += w;                                                               \
    }

__global__ __launch_bounds__(256) void gather_kernel(const unsigned* __restrict__ wcsr,
                                                     const int* __restrict__ offsets,
                                                     const int* __restrict__ counts,
                                                     const __half* __restrict__ xp,
                                                     const float* __restrict__ bias,
                                                     float* __restrict__ out) {
    __shared__ unsigned stage[4][64];
    int wave = threadIdx.x >> 6, lane = threadIdx.x & 63;
    int d = blockIdx.x * 4 + wave;
    if (d >= N_NODES) return;
    int start = offsets[d], cnt = counts[d];
    int o = lane >> 3, f8 = lane & 7;          // stream o, feature-oct f8
    const uint4* xp4 = (const uint4*)xp;       // 16 B = 8 halves
    float a0 = 0.f, a1 = 0.f, a2 = 0.f, a3 = 0.f;
    float a4 = 0.f, a5 = 0.f, a6 = 0.f, a7 = 0.f;
    float ws = 0.f;

    for (int jb = 0; jb < cnt; jb += 64) {
        int iters = min(cnt - jb, 64);
        stage[wave][lane] = (lane < iters) ? wcsr[start + jb + lane] : 0u;
        // wave-private row: in-order within wave, no barrier needed
        unsigned u0 = stage[wave][o];
        unsigned u1 = stage[wave][o + 8];
        unsigned u2 = stage[wave][o + 16];
        unsigned u3 = stage[wave][o + 24];
        unsigned u4 = stage[wave][o + 32];
        unsigned u5 = stage[wave][o + 40];
        unsigned u6 = stage[wave][o + 48];
        unsigned u7 = stage[wave][o + 56];
        uint4 h0 = xp4[(u0 & 0xFFFFu) * 8 + f8];
        uint4 h1 = xp4[(u1 & 0xFFFFu) * 8 + f8];
        uint4 h2 = xp4[(u2 & 0xFFFFu) * 8 + f8];
        uint4 h3 = xp4[(u3 & 0xFFFFu) * 8 + f8];
        uint4 h4 = xp4[(u4 & 0xFFFFu) * 8 + f8];
        uint4 h5 = xp4[(u5 & 0xFFFFu) * 8 + f8];
        uint4 h6 = xp4[(u6 & 0xFFFFu) * 8 + f8];
        uint4 h7 = xp4[(u7 & 0xFFFFu) * 8 + f8];
        // padded entries are u=0 -> w=0 (harmless hot-line loads of row 0)
        CONS(u0, h0);
        CONS(u1, h1);
        CONS(u2, h2);
        CONS(u3, h3);
        CONS(u4, h4);
        CONS(u5, h5);
        CONS(u6, h6);
        CONS(u7, h7);
    }
    // reduce across the 8 streams (lanes differing in bits 3..5)
#pragma unroll
    for (int off = 8; off < 64; off <<= 1) {
        a0 += __shfl_xor(a0, off);
        a1 += __shfl_xor(a1, off);
        a2 += __shfl_xor(a2, off);
        a3 += __shfl_xor(a3, off);
        a4 += __shfl_xor(a4, off);
        a5 += __shfl_xor(a5, off);
        a6 += __shfl_xor(a6, off);
        a7 += __shfl_xor(a7, off);
        ws += __shfl_xor(ws, off);
    }
    if (o == 0) {
        float inv = 1.f / ws;
        float4 b0 = ((const float4*)bias)[f8 * 2];
        float4 b1 = ((const float4*)bias)[f8 * 2 + 1];
        float4 o0, o1;
        o0.x = fmaf(a0, inv, b0.x); o0.y = fmaf(a1, inv, b0.y);
        o0.z = fmaf(a2, inv, b0.z); o0.w = fmaf(a3, inv, b0.w);
        o1.x = fmaf(a4, inv, b1.x); o1.y = fmaf(a5, inv, b1.y);
        o1.z = fmaf(a6, inv, b1.z); o1.w = fmaf(a7, inv, b1.w);
        o0.x = o0.x > 0.f ? o0.x : 0.f;
        o0.y = o0.y > 0.f ? o0.y : 0.f;
        o0.z = o0.z > 0.f ? o0.z : 0.f;
        o0.w = o0.w > 0.f ? o0.w : 0.f;
        o1.x = o1.x > 0.f ? o1.x : 0.f;
        o1.y = o1.y > 0.f ? o1.y : 0.f;
        o1.z = o1.z > 0.f ? o1.z : 0.f;
        o1.w = o1.w > 0.f ? o1.w : 0.f;
        ((float4*)out)[(size_t)d * 16 + f8 * 2]     = o0;
        ((float4*)out)[(size_t)d * 16 + f8 * 2 + 1] = o1;
    }
}

extern "C" void kernel_launch(void* const* d_in, const int* in_sizes, int n_in,
                              void* d_out, int out_size, void* d_ws, size_t ws_size,
                              hipStream_t stream) {
    const float* x     = (const float*)d_in[0];
    const float* W     = (const float*)d_in[1];
    const float* a_src = (const float*)d_in[2];
    const float* a_dst = (const float*)d_in[3];
    const float* bias  = (const float*)d_in[4];
    const int*   ei    = (const int*)d_in[5];
    float* out = (float*)d_out;

    _Float16* xph   = (_Float16*)d_ws;                        // N*64 fp16
    float*  as      = (float*)(xph + (size_t)N_NODES * F_OUT);
    float*  ad      = as + N_NODES;
    int*    counts  = (int*)(ad + N_NODES);                   // N
    int*    offsets = counts + N_NODES;                       // N
    int*    bcur    = offsets + N_NODES;                      // NBUCK
    unsigned* rec   = (unsigned*)(bcur + NBUCK + 64);         // NBUCK*CAP u32
    unsigned* wcsr  = rec + (size_t)NBUCK * CAP;              // NBUCK*CAP u32

    gemm_kernel<<<(N_NODES + 63) / 64, 256, 0, stream>>>(
        (const float4*)x, W, a_src, a_dst, xph, as, ad, bcur);
    part_kernel<<<PBLOCKS, 256, 0, stream>>>(ei, bcur, rec);
    csrb_kernel<<<NBUCK, 256, 0, stream>>>(rec, bcur, as, ad, offsets, counts, wcsr);
    gather_kernel<<<(N_NODES + 3) / 4, 256, 0, stream>>>(wcsr, offsets, counts,
                                                         (const __half*)xph, bias, out);
}

// Round 16
// 82.554 us; speedup vs baseline: 1.6424x; 1.6424x over previous
//
#include <hip/hip_runtime.h>
#include <hip/hip_fp16.h>
#include <math.h>

#define N_NODES 50000
#define N_EDGES 1600000
#define ET (N_EDGES + N_NODES)
#define F_OUT 64
#define F_IN 128
#define SLOPE 0.2f
#define BSHIFT 7                               // 128 nodes per bucket
#define BNODES 128
#define NBUCK ((N_NODES + BNODES - 1) >> BSHIFT)   // 391 buckets
#define CAP 4736                               // mean 4224 + 8 sigma
#define EPB 4096                               // edges per partition block
#define PBLOCKS ((ET + EPB - 1) / EPB)         // 403

typedef _Float16 half8 __attribute__((ext_vector_type(8)));
typedef _Float16 half4 __attribute__((ext_vector_type(4)));
typedef float f32x4 __attribute__((ext_vector_type(4)));

// ---------------- MFMA GEMM: xp(f16) = x @ W + attention logits (+bcur zero) ----------------
__global__ __launch_bounds__(256) void gemm_kernel(const float4* __restrict__ x4,
                                                   const float* __restrict__ W,
                                                   const float* __restrict__ a_src,
                                                   const float* __restrict__ a_dst,
                                                   _Float16* __restrict__ xph,
                                                   float* __restrict__ alpha_s,
                                                   float* __restrict__ alpha_d,
                                                   int* __restrict__ bcur) {
    __shared__ _Float16 xs[64][136];          // padded: row stride 272B
    int t = threadIdx.x;
    if (blockIdx.x == 0)
        for (int i = t; i < NBUCK; i += 256) bcur[i] = 0;
    int wave = t >> 6, lane = t & 63;
    int g = lane >> 4, c16 = lane & 15;

    size_t rbase = (size_t)blockIdx.x * 64;
#pragma unroll
    for (int i = 0; i < 8; ++i) {
        int idx = t + i * 256;                 // over 64*32 float4
        int row = idx >> 5, c4 = idx & 31;
        size_t gr = rbase + row;
        if (gr >= N_NODES) gr = N_NODES - 1;
        float4 v = x4[gr * (F_IN / 4) + c4];
        half4 hv = { (_Float16)v.x, (_Float16)v.y, (_Float16)v.z, (_Float16)v.w };
        *(half4*)&xs[row][c4 * 4] = hv;
    }

    // B fragments straight from global W (L2-resident 32 KB)
    half8 bw[4][4];
#pragma unroll
    for (int nt = 0; nt < 4; ++nt)
#pragma unroll
        for (int kt = 0; kt < 4; ++kt) {
            int col = nt * 16 + c16;
            int k0 = kt * 32 + g * 8;
#pragma unroll
            for (int e = 0; e < 8; ++e)
                bw[nt][kt][e] = (_Float16)W[(k0 + e) * F_OUT + col];
        }
    __syncthreads();

    int r0 = wave * 16;
    half8 af[4];
#pragma unroll
    for (int kt = 0; kt < 4; ++kt)
        af[kt] = *(const half8*)&xs[r0 + c16][kt * 32 + g * 8];

    f32x4 acc[4];
#pragma unroll
    for (int nt = 0; nt < 4; ++nt) {
        acc[nt] = (f32x4){0.f, 0.f, 0.f, 0.f};
#pragma unroll
        for (int kt = 0; kt < 4; ++kt)
            acc[nt] = __builtin_amdgcn_mfma_f32_16x16x32_f16(af[kt], bw[nt][kt], acc[nt], 0, 0, 0);
    }

    int growbase = (int)rbase + r0 + g * 4;
#pragma unroll
    for (int nt = 0; nt < 4; ++nt) {
#pragma unroll
        for (int r = 0; r < 4; ++r) {
            int row = growbase + r;
            if (row < N_NODES)
                xph[(size_t)row * F_OUT + nt * 16 + c16] = (_Float16)acc[nt][r];
        }
    }
    float asl[4], adl[4];
#pragma unroll
    for (int nt = 0; nt < 4; ++nt) {
        asl[nt] = a_src[nt * 16 + c16];
        adl[nt] = a_dst[nt * 16 + c16];
    }
#pragma unroll
    for (int r = 0; r < 4; ++r) {
        float ps = 0.f, pd = 0.f;
#pragma unroll
        for (int nt = 0; nt < 4; ++nt) {
            ps = fmaf(acc[nt][r], asl[nt], ps);
            pd = fmaf(acc[nt][r], adl[nt], pd);
        }
#pragma unroll
        for (int off = 1; off < 16; off <<= 1) {
            ps += __shfl_xor(ps, off);
            pd += __shfl_xor(pd, off);
        }
        int row = growbase + r;
        if (c16 == 0 && row < N_NODES) { alpha_s[row] = ps; alpha_d[row] = pd; }
    }
}

// ---------------- partition: single-pass rank capture, 512 threads, 8 edges/thread ----------------
__global__ __launch_bounds__(512) void part_kernel(const int* __restrict__ ei,
                                                   int* __restrict__ bcur,
                                                   unsigned* __restrict__ rec) {
    __shared__ int lc[NBUCK];
    __shared__ int lbase[NBUCK];
    int t = threadIdx.x;
    for (int b = t; b < NBUCK; b += 512) lc[b] = 0;
    __syncthreads();
    int e0 = blockIdx.x * EPB;

    unsigned u[8]; short bk[8]; unsigned short rk[8];
#pragma unroll
    for (int k = 0; k < 2; ++k) {
        int e = e0 + k * 2048 + t * 4;
        int4 sv, dv;
        if (e + 3 < N_EDGES) {                 // fast path: 16B aligned vector loads
            sv = *(const int4*)&ei[e];
            dv = *(const int4*)&ei[N_EDGES + e];
        } else {
            int* sp = (int*)&sv; int* dp = (int*)&dv;
#pragma unroll
            for (int j = 0; j < 4; ++j) {
                int ee = e + j;
                if (ee < N_EDGES)      { sp[j] = ei[ee]; dp[j] = ei[N_EDGES + ee]; }
                else if (ee < ET)      { sp[j] = dp[j] = ee - N_EDGES; }
                else                   { sp[j] = dp[j] = -1; }
            }
        }
        const int* sp = (const int*)&sv; const int* dp = (const int*)&dv;
#pragma unroll
        for (int j = 0; j < 4; ++j) {
            int i = k * 4 + j;
            int d = dp[j];
            if (d >= 0) {
                int b = d >> BSHIFT;
                bk[i] = (short)b;
                rk[i] = (unsigned short)atomicAdd(&lc[b], 1);
                u[i] = (unsigned)sp[j] | ((unsigned)d << 16);
            } else bk[i] = -1;
        }
    }
    __syncthreads();
    for (int b = t; b < NBUCK; b += 512)
        lbase[b] = lc[b] ? (b * CAP + atomicAdd(&bcur[b], lc[b])) : 0;
    __syncthreads();
#pragma unroll
    for (int i = 0; i < 8; ++i)
        if (bk[i] >= 0) rec[lbase[bk[i]] + rk[i]] = u[i];
}

// ---------------- scan helper (8 waves) ----------------
__device__ __forceinline__ int block_incl_scan(int v, int t, int* wsum) {
    int lane = t & 63, wave = t >> 6;
#pragma unroll
    for (int off = 1; off < 64; off <<= 1) {
        int n = __shfl_up(v, off);
        if (lane >= off) v += n;
    }
    if (lane == 63) wsum[wave] = v;
    __syncthreads();
    int add = 0;
    for (int w = 0; w < wave; ++w) add += wsum[w];
    return v + add;
}

// ---------------- per-bucket CSR build + edge-weight precompute ----------------
__global__ __launch_bounds__(512) void csrb_kernel(const unsigned* __restrict__ rec,
                                                   const int* __restrict__ bcur,
                                                   const float* __restrict__ as,
                                                   const float* __restrict__ ad,
                                                   int* __restrict__ offsets,
                                                   int* __restrict__ counts,
                                                   unsigned* __restrict__ wcsr) {
    __shared__ unsigned lrec[CAP];            // 18.9 KB
    __shared__ int lcnt[BNODES], loff[BNODES], lcur[BNODES];
    __shared__ float adl[BNODES];
    __shared__ int wsum[8];
    int t = threadIdx.x;
    int b = blockIdx.x;
    int n0 = b << BSHIFT;
    int r0 = b * CAP;
    int cnt_b = bcur[b];
    if (t < BNODES) {
        lcnt[t] = 0; lcur[t] = 0;
        adl[t] = (n0 + t < N_NODES) ? ad[n0 + t] : 0.f;
    }
    for (int i = t; i < cnt_b; i += 512) lrec[i] = rec[r0 + i];
    __syncthreads();
    for (int i = t; i < cnt_b; i += 512)
        atomicAdd(&lcnt[(lrec[i] >> 16) & (BNODES - 1)], 1);
    __syncthreads();
    int v = (t < BNODES) ? lcnt[t] : 0;
    int incl = block_incl_scan(v, t, wsum);
    if (t < BNODES) {
        loff[t] = incl - v;
        if (n0 + t < N_NODES) { counts[n0 + t] = v; offsets[n0 + t] = r0 + incl - v; }
    }
    __syncthreads();
    for (int i = t; i < cnt_b; i += 512) {
        unsigned u = lrec[i];
        int dl = (u >> 16) & (BNODES - 1);
        int s = u & 0xFFFFu;
        float ev = as[s] + adl[dl];
        ev = ev > 0.f ? ev : SLOPE * ev;
        float w = __expf(ev);
        int pos = atomicAdd(&lcur[dl], 1);
        wcsr[r0 + loff[dl] + pos] =
            (unsigned)s | ((unsigned)__half_as_ushort(__float2half(w)) << 16);
    }
}

// ---------------- gather: wave/dst, 8 edge-streams x 8 lanes, uint4 row loads ----------------
#define CONS(u_, h_)                                                           \
    {                                                                          \
        float w = __half2float(__ushort_as_half((unsigned short)((u_) >> 16)));\
        float2 p;                                                              \
        p = __half22float2(__builtin_bit_cast(__half2, (h_).x));               \
        a0 = fmaf(w, p.x, a0); a1 = fmaf(w, p.y, a1);                          \
        p = __half22float2(__builtin_bit_cast(__half2, (h_).y));               \
        a2 = fmaf(w, p.x, a2); a3 = fmaf(w, p.y, a3);                          \
        p = __half22float2(__builtin_bit_cast(__half2, (h_).z));               \
        a4 = fmaf(w, p.x, a4); a5 = fmaf(w, p.y, a5);                          \
        p = __half22float2(__builtin_bit_cast(__half2, (h_).w));               \
        a6 = fmaf(w, p.x, a6); a7 = fmaf(w, p.y, a7);                          \
        ws += w;                                                               \
    }

__global__ __launch_bounds__(256) void gather_kernel(const unsigned* __restrict__ wcsr,
                                                     const int* __restrict__ offsets,
                                                     const int* __restrict__ counts,
                                                     const __half* __restrict__ xp,
                                                     const float* __restrict__ bias,
                                                     float* __restrict__ out) {
    __shared__ unsigned stage[4][64];
    int wave = threadIdx.x >> 6, lane = threadIdx.x & 63;
    int d = blockIdx.x * 4 + wave;
    if (d >= N_NODES) return;
    int start = offsets[d], cnt = counts[d];
    int o = lane >> 3, f8 = lane & 7;          // stream o, feature-oct f8
    const uint4* xp4 = (const uint4*)xp;       // 16 B = 8 halves
    float a0 = 0.f, a1 = 0.f, a2 = 0.f, a3 = 0.f;
    float a4 = 0.f, a5 = 0.f, a6 = 0.f, a7 = 0.f;
    float ws = 0.f;

    for (int jb = 0; jb < cnt; jb += 64) {
        int iters = min(cnt - jb, 64);
        stage[wave][lane] = (lane < iters) ? wcsr[start + jb + lane] : 0u;
        // wave-private row: in-order within wave, no barrier needed
        unsigned u0 = stage[wave][o];
        unsigned u1 = stage[wave][o + 8];
        unsigned u2 = stage[wave][o + 16];
        unsigned u3 = stage[wave][o + 24];
        unsigned u4 = stage[wave][o + 32];
        unsigned u5 = stage[wave][o + 40];
        unsigned u6 = stage[wave][o + 48];
        unsigned u7 = stage[wave][o + 56];
        uint4 h0 = xp4[(u0 & 0xFFFFu) * 8 + f8];
        uint4 h1 = xp4[(u1 & 0xFFFFu) * 8 + f8];
        uint4 h2 = xp4[(u2 & 0xFFFFu) * 8 + f8];
        uint4 h3 = xp4[(u3 & 0xFFFFu) * 8 + f8];
        uint4 h4 = xp4[(u4 & 0xFFFFu) * 8 + f8];
        uint4 h5 = xp4[(u5 & 0xFFFFu) * 8 + f8];
        uint4 h6 = xp4[(u6 & 0xFFFFu) * 8 + f8];
        uint4 h7 = xp4[(u7 & 0xFFFFu) * 8 + f8];
        // padded entries are u=0 -> w=0 (harmless hot-line loads of row 0)
        CONS(u0, h0);
        CONS(u1, h1);
        CONS(u2, h2);
        CONS(u3, h3);
        CONS(u4, h4);
        CONS(u5, h5);
        CONS(u6, h6);
        CONS(u7, h7);
    }
    // reduce across the 8 streams (lanes differing in bits 3..5)
#pragma unroll
    for (int off = 8; off < 64; off <<= 1) {
        a0 += __shfl_xor(a0, off);
        a1 += __shfl_xor(a1, off);
        a2 += __shfl_xor(a2, off);
        a3 += __shfl_xor(a3, off);
        a4 += __shfl_xor(a4, off);
        a5 += __shfl_xor(a5, off);
        a6 += __shfl_xor(a6, off);
        a7 += __shfl_xor(a7, off);
        ws += __shfl_xor(ws, off);
    }
    if (o == 0) {
        float inv = 1.f / ws;
        float4 b0 = ((const float4*)bias)[f8 * 2];
        float4 b1 = ((const float4*)bias)[f8 * 2 + 1];
        float4 o0, o1;
        o0.x = fmaf(a0, inv, b0.x); o0.y = fmaf(a1, inv, b0.y);
        o0.z = fmaf(a2, inv, b0.z); o0.w = fmaf(a3, inv, b0.w);
        o1.x = fmaf(a4, inv, b1.x); o1.y = fmaf(a5, inv, b1.y);
        o1.z = fmaf(a6, inv, b1.z); o1.w = fmaf(a7, inv, b1.w);
        o0.x = o0.x > 0.f ? o0.x : 0.f;
        o0.y = o0.y > 0.f ? o0.y : 0.f;
        o0.z = o0.z > 0.f ? o0.z : 0.f;
        o0.w = o0.w > 0.f ? o0.w : 0.f;
        o1.x = o1.x > 0.f ? o1.x : 0.f;
        o1.y = o1.y > 0.f ? o1.y : 0.f;
        o1.z = o1.z > 0.f ? o1.z : 0.f;
        o1.w = o1.w > 0.f ? o1.w : 0.f;
        ((float4*)out)[(size_t)d * 16 + f8 * 2]     = o0;
        ((float4*)out)[(size_t)d * 16 + f8 * 2 + 1] = o1;
    }
}

extern "C" void kernel_launch(void* const* d_in, const int* in_sizes, int n_in,
                              void* d_out, int out_size, void* d_ws, size_t ws_size,
                              hipStream_t stream) {
    const float* x     = (const float*)d_in[0];
    const float* W     = (const float*)d_in[1];
    const float* a_src = (const float*)d_in[2];
    const float* a_dst = (const float*)d_in[3];
    const float* bias  = (const float*)d_in[4];
    const int*   ei    = (const int*)d_in[5];
    float* out = (float*)d_out;

    _Float16* xph   = (_Float16*)d_ws;                        // N*64 fp16
    float*  as      = (float*)(xph + (size_t)N_NODES * F_OUT);
    float*  ad      = as + N_NODES;
    int*    counts  = (int*)(ad + N_NODES);                   // N
    int*    offsets = counts + N_NODES;                       // N
    int*    bcur    = offsets + N_NODES;                      // NBUCK
    unsigned* rec   = (unsigned*)(bcur + NBUCK + 64);         // NBUCK*CAP u32
    unsigned* wcsr  = rec + (size_t)NBUCK * CAP;              // NBUCK*CAP u32

    gemm_kernel<<<(N_NODES + 63) / 64, 256, 0, stream>>>(
        (const float4*)x, W, a_src, a_dst, xph, as, ad, bcur);
    part_kernel<<<PBLOCKS, 512, 0, stream>>>(ei, bcur, rec);
    csrb_kernel<<<NBUCK, 512, 0, stream>>>(rec, bcur, as, ad, offsets, counts, wcsr);
    gather_kernel<<<(N_NODES + 3) / 4, 256, 0, stream>>>(wcsr, offsets, counts,
                                                         (const __half*)xph, bias, out);
}

// Round 17
// 80.330 us; speedup vs baseline: 1.6879x; 1.0277x over previous
//
#include <hip/hip_runtime.h>
#include <hip/hip_fp16.h>
#include <math.h>

#define N_NODES 50000
#define N_EDGES 1600000
#define ET (N_EDGES + N_NODES)
#define F_OUT 64
#define F_IN 128
#define SLOPE 0.2f
#define BSHIFT 7                               // 128 nodes per bucket
#define BNODES 128
#define NBUCK ((N_NODES + BNODES - 1) >> BSHIFT)   // 391 buckets
#define CAP 4736                               // mean 4224 + 8 sigma
#define EPB 4096                               // edges per partition block
#define PBLOCKS ((ET + EPB - 1) / EPB)         // 403

typedef _Float16 half8 __attribute__((ext_vector_type(8)));
typedef _Float16 half4 __attribute__((ext_vector_type(4)));
typedef _Float16 half2v __attribute__((ext_vector_type(2)));
typedef float f32x4 __attribute__((ext_vector_type(4)));

// ---------------- MFMA GEMM: xp(f16) = x @ W + attention logits (+bcur zero) ----------------
__global__ __launch_bounds__(256) void gemm_kernel(const float4* __restrict__ x4,
                                                   const float* __restrict__ W,
                                                   const float* __restrict__ a_src,
                                                   const float* __restrict__ a_dst,
                                                   _Float16* __restrict__ xph,
                                                   float* __restrict__ alpha_s,
                                                   float* __restrict__ alpha_d,
                                                   int* __restrict__ bcur) {
    __shared__ _Float16 xs[64][136];          // padded: row stride 272B
    int t = threadIdx.x;
    if (blockIdx.x == 0)
        for (int i = t; i < NBUCK; i += 256) bcur[i] = 0;
    int wave = t >> 6, lane = t & 63;
    int g = lane >> 4, c16 = lane & 15;

    size_t rbase = (size_t)blockIdx.x * 64;
#pragma unroll
    for (int i = 0; i < 8; ++i) {
        int idx = t + i * 256;                 // over 64*32 float4
        int row = idx >> 5, c4 = idx & 31;
        size_t gr = rbase + row;
        if (gr >= N_NODES) gr = N_NODES - 1;
        float4 v = x4[gr * (F_IN / 4) + c4];
        half4 hv = { (_Float16)v.x, (_Float16)v.y, (_Float16)v.z, (_Float16)v.w };
        *(half4*)&xs[row][c4 * 4] = hv;
    }

    // B fragments straight from global W (L2-resident 32 KB)
    half8 bw[4][4];
#pragma unroll
    for (int nt = 0; nt < 4; ++nt)
#pragma unroll
        for (int kt = 0; kt < 4; ++kt) {
            int col = nt * 16 + c16;
            int k0 = kt * 32 + g * 8;
#pragma unroll
            for (int e = 0; e < 8; ++e)
                bw[nt][kt][e] = (_Float16)W[(k0 + e) * F_OUT + col];
        }
    __syncthreads();

    int r0 = wave * 16;
    half8 af[4];
#pragma unroll
    for (int kt = 0; kt < 4; ++kt)
        af[kt] = *(const half8*)&xs[r0 + c16][kt * 32 + g * 8];

    f32x4 acc[4];
#pragma unroll
    for (int nt = 0; nt < 4; ++nt) {
        acc[nt] = (f32x4){0.f, 0.f, 0.f, 0.f};
#pragma unroll
        for (int kt = 0; kt < 4; ++kt)
            acc[nt] = __builtin_amdgcn_mfma_f32_16x16x32_f16(af[kt], bw[nt][kt], acc[nt], 0, 0, 0);
    }

    int growbase = (int)rbase + r0 + g * 4;
#pragma unroll
    for (int nt = 0; nt < 4; ++nt) {
#pragma unroll
        for (int r = 0; r < 4; ++r) {
            int row = growbase + r;
            if (row < N_NODES)
                xph[(size_t)row * F_OUT + nt * 16 + c16] = (_Float16)acc[nt][r];
        }
    }
    float asl[4], adl[4];
#pragma unroll
    for (int nt = 0; nt < 4; ++nt) {
        asl[nt] = a_src[nt * 16 + c16];
        adl[nt] = a_dst[nt * 16 + c16];
    }
#pragma unroll
    for (int r = 0; r < 4; ++r) {
        float ps = 0.f, pd = 0.f;
#pragma unroll
        for (int nt = 0; nt < 4; ++nt) {
            ps = fmaf(acc[nt][r], asl[nt], ps);
            pd = fmaf(acc[nt][r], adl[nt], pd);
        }
#pragma unroll
        for (int off = 1; off < 16; off <<= 1) {
            ps += __shfl_xor(ps, off);
            pd += __shfl_xor(pd, off);
        }
        int row = growbase + r;
        if (c16 == 0 && row < N_NODES) { alpha_s[row] = ps; alpha_d[row] = pd; }
    }
}

// ---------------- partition: single-pass rank capture, 512 threads, 8 edges/thread ----------------
__global__ __launch_bounds__(512) void part_kernel(const int* __restrict__ ei,
                                                   int* __restrict__ bcur,
                                                   unsigned* __restrict__ rec) {
    __shared__ int lc[NBUCK];
    __shared__ int lbase[NBUCK];
    int t = threadIdx.x;
    for (int b = t; b < NBUCK; b += 512) lc[b] = 0;
    __syncthreads();
    int e0 = blockIdx.x * EPB;

    unsigned u[8]; short bk[8]; unsigned short rk[8];
#pragma unroll
    for (int k = 0; k < 2; ++k) {
        int e = e0 + k * 2048 + t * 4;
        int4 sv, dv;
        if (e + 3 < N_EDGES) {                 // fast path: 16B aligned vector loads
            sv = *(const int4*)&ei[e];
            dv = *(const int4*)&ei[N_EDGES + e];
        } else {
            int* sp = (int*)&sv; int* dp = (int*)&dv;
#pragma unroll
            for (int j = 0; j < 4; ++j) {
                int ee = e + j;
                if (ee < N_EDGES)      { sp[j] = ei[ee]; dp[j] = ei[N_EDGES + ee]; }
                else if (ee < ET)      { sp[j] = dp[j] = ee - N_EDGES; }
                else                   { sp[j] = dp[j] = -1; }
            }
        }
        const int* sp = (const int*)&sv; const int* dp = (const int*)&dv;
#pragma unroll
        for (int j = 0; j < 4; ++j) {
            int i = k * 4 + j;
            int d = dp[j];
            if (d >= 0) {
                int b = d >> BSHIFT;
                bk[i] = (short)b;
                rk[i] = (unsigned short)atomicAdd(&lc[b], 1);
                u[i] = (unsigned)sp[j] | ((unsigned)d << 16);
            } else bk[i] = -1;
        }
    }
    __syncthreads();
    for (int b = t; b < NBUCK; b += 512)
        lbase[b] = lc[b] ? (b * CAP + atomicAdd(&bcur[b], lc[b])) : 0;
    __syncthreads();
#pragma unroll
    for (int i = 0; i < 8; ++i)
        if (bk[i] >= 0) rec[lbase[bk[i]] + rk[i]] = u[i];
}

// ---------------- scan helper (8 waves) ----------------
__device__ __forceinline__ int block_incl_scan(int v, int t, int* wsum) {
    int lane = t & 63, wave = t >> 6;
#pragma unroll
    for (int off = 1; off < 64; off <<= 1) {
        int n = __shfl_up(v, off);
        if (lane >= off) v += n;
    }
    if (lane == 63) wsum[wave] = v;
    __syncthreads();
    int add = 0;
    for (int w = 0; w < wave; ++w) add += wsum[w];
    return v + add;
}

// ---------------- per-bucket CSR build + edge-weight precompute ----------------
__global__ __launch_bounds__(512) void csrb_kernel(const unsigned* __restrict__ rec,
                                                   const int* __restrict__ bcur,
                                                   const float* __restrict__ as,
                                                   const float* __restrict__ ad,
                                                   int* __restrict__ offsets,
                                                   int* __restrict__ counts,
                                                   unsigned* __restrict__ wcsr) {
    __shared__ unsigned lrec[CAP];            // 18.9 KB
    __shared__ int lcnt[BNODES], loff[BNODES], lcur[BNODES];
    __shared__ float adl[BNODES];
    __shared__ int wsum[8];
    int t = threadIdx.x;
    int b = blockIdx.x;
    int n0 = b << BSHIFT;
    int r0 = b * CAP;
    int cnt_b = bcur[b];
    if (t < BNODES) {
        lcnt[t] = 0; lcur[t] = 0;
        adl[t] = (n0 + t < N_NODES) ? ad[n0 + t] : 0.f;
    }
    for (int i = t; i < cnt_b; i += 512) lrec[i] = rec[r0 + i];
    __syncthreads();
    for (int i = t; i < cnt_b; i += 512)
        atomicAdd(&lcnt[(lrec[i] >> 16) & (BNODES - 1)], 1);
    __syncthreads();
    int v = (t < BNODES) ? lcnt[t] : 0;
    int incl = block_incl_scan(v, t, wsum);
    if (t < BNODES) {
        loff[t] = incl - v;
        if (n0 + t < N_NODES) { counts[n0 + t] = v; offsets[n0 + t] = r0 + incl - v; }
    }
    __syncthreads();
    for (int i = t; i < cnt_b; i += 512) {
        unsigned u = lrec[i];
        int dl = (u >> 16) & (BNODES - 1);
        int s = u & 0xFFFFu;
        float ev = as[s] + adl[dl];
        ev = ev > 0.f ? ev : SLOPE * ev;
        float w = __expf(ev);
        int pos = atomicAdd(&lcur[dl], 1);
        wcsr[r0 + loff[dl] + pos] =
            (unsigned)s | ((unsigned)__half_as_ushort(__float2half(w)) << 16);
    }
}

// ---------------- gather: wave/dst, 8 streams x 8 lanes, edge-paired v_dot2_f32_f16 ----------------
// For pair (A,B): wpair=(wA,wB); per dword k: plo=(fA_2k,fB_2k), phi=(fA_2k+1,fB_2k+1);
// acc += dot2(p, wpair). ws += dot2(ones, wpair). Padded entries have u=0 -> w=0.
#define H2(x_) __builtin_bit_cast(half2v, (x_))
#define CONS2(uA_, hA_, uB_, hB_)                                              \
    {                                                                          \
        unsigned wp_ = __builtin_amdgcn_perm((uB_), (uA_), 0x07060302u);       \
        half2v wh_ = H2(wp_);                                                  \
        unsigned lo_, hi_;                                                     \
        lo_ = __builtin_amdgcn_perm((hB_).x, (hA_).x, 0x05040100u);            \
        hi_ = __builtin_amdgcn_perm((hB_).x, (hA_).x, 0x07060302u);            \
        a0 = __builtin_amdgcn_fdot2(H2(lo_), wh_, a0, false);                  \
        a1 = __builtin_amdgcn_fdot2(H2(hi_), wh_, a1, false);                  \
        lo_ = __builtin_amdgcn_perm((hB_).y, (hA_).y, 0x05040100u);            \
        hi_ = __builtin_amdgcn_perm((hB_).y, (hA_).y, 0x07060302u);            \
        a2 = __builtin_amdgcn_fdot2(H2(lo_), wh_, a2, false);                  \
        a3 = __builtin_amdgcn_fdot2(H2(hi_), wh_, a3, false);                  \
        lo_ = __builtin_amdgcn_perm((hB_).z, (hA_).z, 0x05040100u);            \
        hi_ = __builtin_amdgcn_perm((hB_).z, (hA_).z, 0x07060302u);            \
        a4 = __builtin_amdgcn_fdot2(H2(lo_), wh_, a4, false);                  \
        a5 = __builtin_amdgcn_fdot2(H2(hi_), wh_, a5, false);                  \
        lo_ = __builtin_amdgcn_perm((hB_).w, (hA_).w, 0x05040100u);            \
        hi_ = __builtin_amdgcn_perm((hB_).w, (hA_).w, 0x07060302u);            \
        a6 = __builtin_amdgcn_fdot2(H2(lo_), wh_, a6, false);                  \
        a7 = __builtin_amdgcn_fdot2(H2(hi_), wh_, a7, false);                  \
        ws = __builtin_amdgcn_fdot2(ones_, wh_, ws, false);                    \
    }

__global__ __launch_bounds__(256) void gather_kernel(const unsigned* __restrict__ wcsr,
                                                     const int* __restrict__ offsets,
                                                     const int* __restrict__ counts,
                                                     const __half* __restrict__ xp,
                                                     const float* __restrict__ bias,
                                                     float* __restrict__ out) {
    __shared__ unsigned stage[4][64];
    int wave = threadIdx.x >> 6, lane = threadIdx.x & 63;
    int d = blockIdx.x * 4 + wave;
    if (d >= N_NODES) return;
    int start = offsets[d], cnt = counts[d];
    int o = lane >> 3, f8 = lane & 7;          // stream o, feature-oct f8
    const uint4* xp4 = (const uint4*)xp;       // 16 B = 8 halves
    const half2v ones_ = { (_Float16)1.f, (_Float16)1.f };
    float a0 = 0.f, a1 = 0.f, a2 = 0.f, a3 = 0.f;
    float a4 = 0.f, a5 = 0.f, a6 = 0.f, a7 = 0.f;
    float ws = 0.f;

    for (int jb = 0; jb < cnt; jb += 64) {
        int iters = min(cnt - jb, 64);
        stage[wave][lane] = (lane < iters) ? wcsr[start + jb + lane] : 0u;
        // wave-private row: in-order within wave, no barrier needed
        unsigned u0 = stage[wave][o];
        unsigned u1 = stage[wave][o + 8];
        unsigned u2 = stage[wave][o + 16];
        unsigned u3 = stage[wave][o + 24];
        unsigned u4 = stage[wave][o + 32];
        unsigned u5 = stage[wave][o + 40];
        unsigned u6 = stage[wave][o + 48];
        unsigned u7 = stage[wave][o + 56];
        uint4 h0 = xp4[(u0 & 0xFFFFu) * 8 + f8];
        uint4 h1 = xp4[(u1 & 0xFFFFu) * 8 + f8];
        uint4 h2 = xp4[(u2 & 0xFFFFu) * 8 + f8];
        uint4 h3 = xp4[(u3 & 0xFFFFu) * 8 + f8];
        uint4 h4 = xp4[(u4 & 0xFFFFu) * 8 + f8];
        uint4 h5 = xp4[(u5 & 0xFFFFu) * 8 + f8];
        uint4 h6 = xp4[(u6 & 0xFFFFu) * 8 + f8];
        uint4 h7 = xp4[(u7 & 0xFFFFu) * 8 + f8];
        CONS2(u0, h0, u1, h1);
        CONS2(u2, h2, u3, h3);
        CONS2(u4, h4, u5, h5);
        CONS2(u6, h6, u7, h7);
    }
    // reduce across the 8 streams (lanes differing in bits 3..5)
#pragma unroll
    for (int off = 8; off < 64; off <<= 1) {
        a0 += __shfl_xor(a0, off);
        a1 += __shfl_xor(a1, off);
        a2 += __shfl_xor(a2, off);
        a3 += __shfl_xor(a3, off);
        a4 += __shfl_xor(a4, off);
        a5 += __shfl_xor(a5, off);
        a6 += __shfl_xor(a6, off);
        a7 += __shfl_xor(a7, off);
        ws += __shfl_xor(ws, off);
    }
    if (o == 0) {
        float inv = 1.f / ws;
        float4 b0 = ((const float4*)bias)[f8 * 2];
        float4 b1 = ((const float4*)bias)[f8 * 2 + 1];
        float4 o0, o1;
        o0.x = fmaf(a0, inv, b0.x); o0.y = fmaf(a1, inv, b0.y);
        o0.z = fmaf(a2, inv, b0.z); o0.w = fmaf(a3, inv, b0.w);
        o1.x = fmaf(a4, inv, b1.x); o1.y = fmaf(a5, inv, b1.y);
        o1.z = fmaf(a6, inv, b1.z); o1.w = fmaf(a7, inv, b1.w);
        o0.x = o0.x > 0.f ? o0.x : 0.f;
        o0.y = o0.y > 0.f ? o0.y : 0.f;
        o0.z = o0.z > 0.f ? o0.z : 0.f;
        o0.w = o0.w > 0.f ? o0.w : 0.f;
        o1.x = o1.x > 0.f ? o1.x : 0.f;
        o1.y = o1.y > 0.f ? o1.y : 0.f;
        o1.z = o1.z > 0.f ? o1.z : 0.f;
        o1.w = o1.w > 0.f ? o1.w : 0.f;
        ((float4*)out)[(size_t)d * 16 + f8 * 2]     = o0;
        ((float4*)out)[(size_t)d * 16 + f8 * 2 + 1] = o1;
    }
}

extern "C" void kernel_launch(void* const* d_in, const int* in_sizes, int n_in,
                              void* d_out, int out_size, void* d_ws, size_t ws_size,
                              hipStream_t stream) {
    const float* x     = (const float*)d_in[0];
    const float* W     = (const float*)d_in[1];
    const float* a_src = (const float*)d_in[2];
    const float* a_dst = (const float*)d_in[3];
    const float* bias  = (const float*)d_in[4];
    const int*   ei    = (const int*)d_in[5];
    float* out = (float*)d_out;

    _Float16* xph   = (_Float16*)d_ws;                        // N*64 fp16
    float*  as      = (float*)(xph + (size_t)N_NODES * F_OUT);
    float*  ad      = as + N_NODES;
    int*    counts  = (int*)(ad + N_NODES);                   // N
    int*    offsets = counts + N_NODES;                       // N
    int*    bcur    = offsets + N_NODES;                      // NBUCK
    unsigned* rec   = (unsigned*)(bcur + NBUCK + 64);         // NBUCK*CAP u32
    unsigned* wcsr  = rec + (size_t)NBUCK * CAP;              // NBUCK*CAP u32

    gemm_kernel<<<(N_NODES + 63) / 64, 256, 0, stream>>>(
        (const float4*)x, W, a_src, a_dst, xph, as, ad, bcur);
    part_kernel<<<PBLOCKS, 512, 0, stream>>>(ei, bcur, rec);
    csrb_kernel<<<NBUCK, 512, 0, stream>>>(rec, bcur, as, ad, offsets, counts, wcsr);
    gather_kernel<<<(N_NODES + 3) / 4, 256, 0, stream>>>(wcsr, offsets, counts,
                                                         (const __half*)xph, bias, out);
}

// Round 18
// 79.665 us; speedup vs baseline: 1.7020x; 1.0084x over previous
//
#include <hip/hip_runtime.h>
#include <hip/hip_fp16.h>
#include <math.h>

#define N_NODES 50000
#define N_EDGES 1600000
#define ET (N_EDGES + N_NODES)
#define F_OUT 64
#define F_IN 128
#define SLOPE 0.2f
#define BSHIFT 7                               // 128 nodes per bucket
#define BNODES 128
#define NBUCK ((N_NODES + BNODES - 1) >> BSHIFT)   // 391 buckets
#define CAP 4736                               // mean 4224 + 8 sigma
#define EPB 4096                               // edges per partition block
#define PBLOCKS ((ET + EPB - 1) / EPB)         // 403

typedef _Float16 half8 __attribute__((ext_vector_type(8)));
typedef _Float16 half4 __attribute__((ext_vector_type(4)));
typedef _Float16 half2v __attribute__((ext_vector_type(2)));
typedef float f32x4 __attribute__((ext_vector_type(4)));

// ---------------- MFMA GEMM: xp(f16) = x @ W + attention logits (+bcur zero) ----------------
__global__ __launch_bounds__(256) void gemm_kernel(const float4* __restrict__ x4,
                                                   const float* __restrict__ W,
                                                   const float* __restrict__ a_src,
                                                   const float* __restrict__ a_dst,
                                                   _Float16* __restrict__ xph,
                                                   float* __restrict__ alpha_s,
                                                   float* __restrict__ alpha_d,
                                                   int* __restrict__ bcur) {
    __shared__ _Float16 xs[64][136];          // padded: row stride 272B
    int t = threadIdx.x;
    if (blockIdx.x == 0)
        for (int i = t; i < NBUCK; i += 256) bcur[i] = 0;
    int wave = t >> 6, lane = t & 63;
    int g = lane >> 4, c16 = lane & 15;

    size_t rbase = (size_t)blockIdx.x * 64;
#pragma unroll
    for (int i = 0; i < 8; ++i) {
        int idx = t + i * 256;                 // over 64*32 float4
        int row = idx >> 5, c4 = idx & 31;
        size_t gr = rbase + row;
        if (gr >= N_NODES) gr = N_NODES - 1;
        float4 v = x4[gr * (F_IN / 4) + c4];
        half4 hv = { (_Float16)v.x, (_Float16)v.y, (_Float16)v.z, (_Float16)v.w };
        *(half4*)&xs[row][c4 * 4] = hv;
    }

    // B fragments straight from global W (L2-resident 32 KB)
    half8 bw[4][4];
#pragma unroll
    for (int nt = 0; nt < 4; ++nt)
#pragma unroll
        for (int kt = 0; kt < 4; ++kt) {
            int col = nt * 16 + c16;
            int k0 = kt * 32 + g * 8;
#pragma unroll
            for (int e = 0; e < 8; ++e)
                bw[nt][kt][e] = (_Float16)W[(k0 + e) * F_OUT + col];
        }
    __syncthreads();

    int r0 = wave * 16;
    half8 af[4];
#pragma unroll
    for (int kt = 0; kt < 4; ++kt)
        af[kt] = *(const half8*)&xs[r0 + c16][kt * 32 + g * 8];

    f32x4 acc[4];
#pragma unroll
    for (int nt = 0; nt < 4; ++nt) {
        acc[nt] = (f32x4){0.f, 0.f, 0.f, 0.f};
#pragma unroll
        for (int kt = 0; kt < 4; ++kt)
            acc[nt] = __builtin_amdgcn_mfma_f32_16x16x32_f16(af[kt], bw[nt][kt], acc[nt], 0, 0, 0);
    }

    int growbase = (int)rbase + r0 + g * 4;
#pragma unroll
    for (int nt = 0; nt < 4; ++nt) {
#pragma unroll
        for (int r = 0; r < 4; ++r) {
            int row = growbase + r;
            if (row < N_NODES)
                xph[(size_t)row * F_OUT + nt * 16 + c16] = (_Float16)acc[nt][r];
        }
    }
    float asl[4], adl[4];
#pragma unroll
    for (int nt = 0; nt < 4; ++nt) {
        asl[nt] = a_src[nt * 16 + c16];
        adl[nt] = a_dst[nt * 16 + c16];
    }
#pragma unroll
    for (int r = 0; r < 4; ++r) {
        float ps = 0.f, pd = 0.f;
#pragma unroll
        for (int nt = 0; nt < 4; ++nt) {
            ps = fmaf(acc[nt][r], asl[nt], ps);
            pd = fmaf(acc[nt][r], adl[nt], pd);
        }
#pragma unroll
        for (int off = 1; off < 16; off <<= 1) {
            ps += __shfl_xor(ps, off);
            pd += __shfl_xor(pd, off);
        }
        int row = growbase + r;
        if (c16 == 0 && row < N_NODES) { alpha_s[row] = ps; alpha_d[row] = pd; }
    }
}

// ---------------- partition: single-pass rank capture, 512 threads, 8 edges/thread ----------------
__global__ __launch_bounds__(512) void part_kernel(const int* __restrict__ ei,
                                                   int* __restrict__ bcur,
                                                   unsigned* __restrict__ rec) {
    __shared__ int lc[NBUCK];
    __shared__ int lbase[NBUCK];
    int t = threadIdx.x;
    for (int b = t; b < NBUCK; b += 512) lc[b] = 0;
    __syncthreads();
    int e0 = blockIdx.x * EPB;

    unsigned u[8]; short bk[8]; unsigned short rk[8];
#pragma unroll
    for (int k = 0; k < 2; ++k) {
        int e = e0 + k * 2048 + t * 4;
        int4 sv, dv;
        if (e + 3 < N_EDGES) {                 // fast path: 16B aligned vector loads
            sv = *(const int4*)&ei[e];
            dv = *(const int4*)&ei[N_EDGES + e];
        } else {
            int* sp = (int*)&sv; int* dp = (int*)&dv;
#pragma unroll
            for (int j = 0; j < 4; ++j) {
                int ee = e + j;
                if (ee < N_EDGES)      { sp[j] = ei[ee]; dp[j] = ei[N_EDGES + ee]; }
                else if (ee < ET)      { sp[j] = dp[j] = ee - N_EDGES; }
                else                   { sp[j] = dp[j] = -1; }
            }
        }
        const int* sp = (const int*)&sv; const int* dp = (const int*)&dv;
#pragma unroll
        for (int j = 0; j < 4; ++j) {
            int i = k * 4 + j;
            int d = dp[j];
            if (d >= 0) {
                int b = d >> BSHIFT;
                bk[i] = (short)b;
                rk[i] = (unsigned short)atomicAdd(&lc[b], 1);
                u[i] = (unsigned)sp[j] | ((unsigned)d << 16);
            } else bk[i] = -1;
        }
    }
    __syncthreads();
    for (int b = t; b < NBUCK; b += 512)
        lbase[b] = lc[b] ? (b * CAP + atomicAdd(&bcur[b], lc[b])) : 0;
    __syncthreads();
#pragma unroll
    for (int i = 0; i < 8; ++i)
        if (bk[i] >= 0) rec[lbase[bk[i]] + rk[i]] = u[i];
}

// ---------------- scan helper (8 waves) ----------------
__device__ __forceinline__ int block_incl_scan(int v, int t, int* wsum) {
    int lane = t & 63, wave = t >> 6;
#pragma unroll
    for (int off = 1; off < 64; off <<= 1) {
        int n = __shfl_up(v, off);
        if (lane >= off) v += n;
    }
    if (lane == 63) wsum[wave] = v;
    __syncthreads();
    int add = 0;
    for (int w = 0; w < wave; ++w) add += wsum[w];
    return v + add;
}

// ---------------- per-bucket CSR build + edge-weight precompute ----------------
__global__ __launch_bounds__(512) void csrb_kernel(const unsigned* __restrict__ rec,
                                                   const int* __restrict__ bcur,
                                                   const float* __restrict__ as,
                                                   const float* __restrict__ ad,
                                                   int* __restrict__ offsets,
                                                   int* __restrict__ counts,
                                                   unsigned* __restrict__ wcsr) {
    __shared__ unsigned lrec[CAP];            // 18.9 KB
    __shared__ int lcnt[BNODES], loff[BNODES], lcur[BNODES];
    __shared__ float adl[BNODES];
    __shared__ int wsum[8];
    int t = threadIdx.x;
    int b = blockIdx.x;
    int n0 = b << BSHIFT;
    int r0 = b * CAP;
    int cnt_b = bcur[b];
    if (t < BNODES) {
        lcnt[t] = 0; lcur[t] = 0;
        adl[t] = (n0 + t < N_NODES) ? ad[n0 + t] : 0.f;
    }
    for (int i = t; i < cnt_b; i += 512) lrec[i] = rec[r0 + i];
    __syncthreads();
    for (int i = t; i < cnt_b; i += 512)
        atomicAdd(&lcnt[(lrec[i] >> 16) & (BNODES - 1)], 1);
    __syncthreads();
    int v = (t < BNODES) ? lcnt[t] : 0;
    int incl = block_incl_scan(v, t, wsum);
    if (t < BNODES) {
        loff[t] = incl - v;
        if (n0 + t < N_NODES) { counts[n0 + t] = v; offsets[n0 + t] = r0 + incl - v; }
    }
    __syncthreads();
    for (int i = t; i < cnt_b; i += 512) {
        unsigned u = lrec[i];
        int dl = (u >> 16) & (BNODES - 1);
        int s = u & 0xFFFFu;
        float ev = as[s] + adl[dl];
        ev = ev > 0.f ? ev : SLOPE * ev;
        float w = __expf(ev);
        int pos = atomicAdd(&lcur[dl], 1);
        wcsr[r0 + loff[dl] + pos] =
            (unsigned)s | ((unsigned)__half_as_ushort(__float2half(w)) << 16);
    }
}

// ---------------- gather: wave/dst, 8 streams x 8 lanes, fdot2 pairs, wave-uniform tiering ----------------
#define H2(x_) __builtin_bit_cast(half2v, (x_))
#define CONS2(uA_, hA_, uB_, hB_)                                              \
    {                                                                          \
        unsigned wp_ = __builtin_amdgcn_perm((uB_), (uA_), 0x07060302u);       \
        half2v wh_ = H2(wp_);                                                  \
        unsigned lo_, hi_;                                                     \
        lo_ = __builtin_amdgcn_perm((hB_).x, (hA_).x, 0x05040100u);            \
        hi_ = __builtin_amdgcn_perm((hB_).x, (hA_).x, 0x07060302u);            \
        a0 = __builtin_amdgcn_fdot2(H2(lo_), wh_, a0, false);                  \
        a1 = __builtin_amdgcn_fdot2(H2(hi_), wh_, a1, false);                  \
        lo_ = __builtin_amdgcn_perm((hB_).y, (hA_).y, 0x05040100u);            \
        hi_ = __builtin_amdgcn_perm((hB_).y, (hA_).y, 0x07060302u);            \
        a2 = __builtin_amdgcn_fdot2(H2(lo_), wh_, a2, false);                  \
        a3 = __builtin_amdgcn_fdot2(H2(hi_), wh_, a3, false);                  \
        lo_ = __builtin_amdgcn_perm((hB_).z, (hA_).z, 0x05040100u);            \
        hi_ = __builtin_amdgcn_perm((hB_).z, (hA_).z, 0x07060302u);            \
        a4 = __builtin_amdgcn_fdot2(H2(lo_), wh_, a4, false);                  \
        a5 = __builtin_amdgcn_fdot2(H2(hi_), wh_, a5, false);                  \
        lo_ = __builtin_amdgcn_perm((hB_).w, (hA_).w, 0x05040100u);            \
        hi_ = __builtin_amdgcn_perm((hB_).w, (hA_).w, 0x07060302u);            \
        a6 = __builtin_amdgcn_fdot2(H2(lo_), wh_, a6, false);                  \
        a7 = __builtin_amdgcn_fdot2(H2(hi_), wh_, a7, false);                  \
        ws = __builtin_amdgcn_fdot2(ones_, wh_, ws, false);                    \
    }

__global__ __launch_bounds__(256) void gather_kernel(const unsigned* __restrict__ wcsr,
                                                     const int* __restrict__ offsets,
                                                     const int* __restrict__ counts,
                                                     const __half* __restrict__ xp,
                                                     const float* __restrict__ bias,
                                                     float* __restrict__ out) {
    __shared__ unsigned stage[4][64];
    int wave = threadIdx.x >> 6, lane = threadIdx.x & 63;
    int d = blockIdx.x * 4 + wave;
    if (d >= N_NODES) return;
    int start = offsets[d], cnt = counts[d];
    int o = lane >> 3, f8 = lane & 7;          // stream o, feature-oct f8
    const uint4* xp4 = (const uint4*)xp;       // 16 B = 8 halves
    const half2v ones_ = { (_Float16)1.f, (_Float16)1.f };
    float a0 = 0.f, a1 = 0.f, a2 = 0.f, a3 = 0.f;
    float a4 = 0.f, a5 = 0.f, a6 = 0.f, a7 = 0.f;
    float ws = 0.f;

    for (int jb = 0; jb < cnt; jb += 64) {
        int iters = min(cnt - jb, 64);
        stage[wave][lane] = (lane < iters) ? wcsr[start + jb + lane] : 0u;
        // records 0..31 live in streams' first 4 slots (u0..u3)
        unsigned u0 = stage[wave][o];
        unsigned u1 = stage[wave][o + 8];
        unsigned u2 = stage[wave][o + 16];
        unsigned u3 = stage[wave][o + 24];
        uint4 h0 = xp4[(u0 & 0xFFFFu) * 8 + f8];
        uint4 h1 = xp4[(u1 & 0xFFFFu) * 8 + f8];
        uint4 h2 = xp4[(u2 & 0xFFFFu) * 8 + f8];
        uint4 h3 = xp4[(u3 & 0xFFFFu) * 8 + f8];
        bool second = iters > 32;              // wave-uniform branch
        unsigned u4, u5, u6, u7;
        uint4 h4, h5, h6, h7;
        if (second) {                          // issue second-half loads early
            u4 = stage[wave][o + 32];
            u5 = stage[wave][o + 40];
            u6 = stage[wave][o + 48];
            u7 = stage[wave][o + 56];
            h4 = xp4[(u4 & 0xFFFFu) * 8 + f8];
            h5 = xp4[(u5 & 0xFFFFu) * 8 + f8];
            h6 = xp4[(u6 & 0xFFFFu) * 8 + f8];
            h7 = xp4[(u7 & 0xFFFFu) * 8 + f8];
        }
        CONS2(u0, h0, u1, h1);
        CONS2(u2, h2, u3, h3);
        if (second) {
            CONS2(u4, h4, u5, h5);
            CONS2(u6, h6, u7, h7);
        }
    }
    // reduce across the 8 streams (lanes differing in bits 3..5)
#pragma unroll
    for (int off = 8; off < 64; off <<= 1) {
        a0 += __shfl_xor(a0, off);
        a1 += __shfl_xor(a1, off);
        a2 += __shfl_xor(a2, off);
        a3 += __shfl_xor(a3, off);
        a4 += __shfl_xor(a4, off);
        a5 += __shfl_xor(a5, off);
        a6 += __shfl_xor(a6, off);
        a7 += __shfl_xor(a7, off);
        ws += __shfl_xor(ws, off);
    }
    if (o == 0) {
        float inv = 1.f / ws;
        float4 b0 = ((const float4*)bias)[f8 * 2];
        float4 b1 = ((const float4*)bias)[f8 * 2 + 1];
        float4 o0, o1;
        o0.x = fmaf(a0, inv, b0.x); o0.y = fmaf(a1, inv, b0.y);
        o0.z = fmaf(a2, inv, b0.z); o0.w = fmaf(a3, inv, b0.w);
        o1.x = fmaf(a4, inv, b1.x); o1.y = fmaf(a5, inv, b1.y);
        o1.z = fmaf(a6, inv, b1.z); o1.w = fmaf(a7, inv, b1.w);
        o0.x = o0.x > 0.f ? o0.x : 0.f;
        o0.y = o0.y > 0.f ? o0.y : 0.f;
        o0.z = o0.z > 0.f ? o0.z : 0.f;
        o0.w = o0.w > 0.f ? o0.w : 0.f;
        o1.x = o1.x > 0.f ? o1.x : 0.f;
        o1.y = o1.y > 0.f ? o1.y : 0.f;
        o1.z = o1.z > 0.f ? o1.z : 0.f;
        o1.w = o1.w > 0.f ? o1.w : 0.f;
        ((float4*)out)[(size_t)d * 16 + f8 * 2]     = o0;
        ((float4*)out)[(size_t)d * 16 + f8 * 2 + 1] = o1;
    }
}

extern "C" void kernel_launch(void* const* d_in, const int* in_sizes, int n_in,
                              void* d_out, int out_size, void* d_ws, size_t ws_size,
                              hipStream_t stream) {
    const float* x     = (const float*)d_in[0];
    const float* W     = (const float*)d_in[1];
    const float* a_src = (const float*)d_in[2];
    const float* a_dst = (const float*)d_in[3];
    const float* bias  = (const float*)d_in[4];
    const int*   ei    = (const int*)d_in[5];
    float* out = (float*)d_out;

    _Float16* xph   = (_Float16*)d_ws;                        // N*64 fp16
    float*  as      = (float*)(xph + (size_t)N_NODES * F_OUT);
    float*  ad      = as + N_NODES;
    int*    counts  = (int*)(ad + N_NODES);                   // N
    int*    offsets = counts + N_NODES;                       // N
    int*    bcur    = offsets + N_NODES;                      // NBUCK
    unsigned* rec   = (unsigned*)(bcur + NBUCK + 64);         // NBUCK*CAP u32
    unsigned* wcsr  = rec + (size_t)NBUCK * CAP;              // NBUCK*CAP u32

    gemm_kernel<<<(N_NODES + 63) / 64, 256, 0, stream>>>(
        (const float4*)x, W, a_src, a_dst, xph, as, ad, bcur);
    part_kernel<<<PBLOCKS, 512, 0, stream>>>(ei, bcur, rec);
    csrb_kernel<<<NBUCK, 512, 0, stream>>>(rec, bcur, as, ad, offsets, counts, wcsr);
    gather_kernel<<<(N_NODES + 3) / 4, 256, 0, stream>>>(wcsr, offsets, counts,
                                                         (const __half*)xph, bias, out);
}

// Round 19
// 76.237 us; speedup vs baseline: 1.7785x; 1.0450x over previous
//
#include <hip/hip_runtime.h>
#include <hip/hip_fp16.h>
#include <math.h>

#define N_NODES 50000
#define N_EDGES 1600000
#define ET (N_EDGES + N_NODES)
#define F_OUT 64
#define F_IN 128
#define SLOPE 0.2f
#define BSHIFT 7                               // 128 nodes per bucket
#define BNODES 128
#define NBUCK ((N_NODES + BNODES - 1) >> BSHIFT)   // 391 buckets
#define CAP 4736                               // mean 4224 + 8 sigma
#define EPB 8192                               // edges per partition block
#define PBLOCKS ((ET + EPB - 1) / EPB)         // 202

typedef _Float16 half8 __attribute__((ext_vector_type(8)));
typedef _Float16 half4 __attribute__((ext_vector_type(4)));
typedef _Float16 half2v __attribute__((ext_vector_type(2)));
typedef float f32x4 __attribute__((ext_vector_type(4)));

// ---------------- MFMA GEMM: xp(f16) = x @ W + attention logits (+bcur zero) ----------------
__global__ __launch_bounds__(256) void gemm_kernel(const float4* __restrict__ x4,
                                                   const float* __restrict__ W,
                                                   const float* __restrict__ a_src,
                                                   const float* __restrict__ a_dst,
                                                   _Float16* __restrict__ xph,
                                                   float* __restrict__ alpha_s,
                                                   float* __restrict__ alpha_d,
                                                   int* __restrict__ bcur) {
    __shared__ _Float16 xs[64][136];          // padded: row stride 272B
    int t = threadIdx.x;
    if (blockIdx.x == 0)
        for (int i = t; i < NBUCK; i += 256) bcur[i] = 0;
    int wave = t >> 6, lane = t & 63;
    int g = lane >> 4, c16 = lane & 15;

    size_t rbase = (size_t)blockIdx.x * 64;
#pragma unroll
    for (int i = 0; i < 8; ++i) {
        int idx = t + i * 256;                 // over 64*32 float4
        int row = idx >> 5, c4 = idx & 31;
        size_t gr = rbase + row;
        if (gr >= N_NODES) gr = N_NODES - 1;
        float4 v = x4[gr * (F_IN / 4) + c4];
        half4 hv = { (_Float16)v.x, (_Float16)v.y, (_Float16)v.z, (_Float16)v.w };
        *(half4*)&xs[row][c4 * 4] = hv;
    }

    // B fragments straight from global W (L2-resident 32 KB)
    half8 bw[4][4];
#pragma unroll
    for (int nt = 0; nt < 4; ++nt)
#pragma unroll
        for (int kt = 0; kt < 4; ++kt) {
            int col = nt * 16 + c16;
            int k0 = kt * 32 + g * 8;
#pragma unroll
            for (int e = 0; e < 8; ++e)
                bw[nt][kt][e] = (_Float16)W[(k0 + e) * F_OUT + col];
        }
    __syncthreads();

    int r0 = wave * 16;
    half8 af[4];
#pragma unroll
    for (int kt = 0; kt < 4; ++kt)
        af[kt] = *(const half8*)&xs[r0 + c16][kt * 32 + g * 8];

    f32x4 acc[4];
#pragma unroll
    for (int nt = 0; nt < 4; ++nt) {
        acc[nt] = (f32x4){0.f, 0.f, 0.f, 0.f};
#pragma unroll
        for (int kt = 0; kt < 4; ++kt)
            acc[nt] = __builtin_amdgcn_mfma_f32_16x16x32_f16(af[kt], bw[nt][kt], acc[nt], 0, 0, 0);
    }

    int growbase = (int)rbase + r0 + g * 4;
#pragma unroll
    for (int nt = 0; nt < 4; ++nt) {
#pragma unroll
        for (int r = 0; r < 4; ++r) {
            int row = growbase + r;
            if (row < N_NODES)
                xph[(size_t)row * F_OUT + nt * 16 + c16] = (_Float16)acc[nt][r];
        }
    }
    float asl[4], adl[4];
#pragma unroll
    for (int nt = 0; nt < 4; ++nt) {
        asl[nt] = a_src[nt * 16 + c16];
        adl[nt] = a_dst[nt * 16 + c16];
    }
#pragma unroll
    for (int r = 0; r < 4; ++r) {
        float ps = 0.f, pd = 0.f;
#pragma unroll
        for (int nt = 0; nt < 4; ++nt) {
            ps = fmaf(acc[nt][r], asl[nt], ps);
            pd = fmaf(acc[nt][r], adl[nt], pd);
        }
#pragma unroll
        for (int off = 1; off < 16; off <<= 1) {
            ps += __shfl_xor(ps, off);
            pd += __shfl_xor(pd, off);
        }
        int row = growbase + r;
        if (c16 == 0 && row < N_NODES) { alpha_s[row] = ps; alpha_d[row] = pd; }
    }
}

// ---------------- partition: single-pass rank capture, 1024 threads, 8 edges/thread ----------------
__global__ __launch_bounds__(1024) void part_kernel(const int* __restrict__ ei,
                                                    int* __restrict__ bcur,
                                                    unsigned* __restrict__ rec) {
    __shared__ int lc[NBUCK];
    __shared__ int lbase[NBUCK];
    int t = threadIdx.x;
    if (t < NBUCK) lc[t] = 0;
    __syncthreads();
    int e0 = blockIdx.x * EPB;

    unsigned u[8]; short bk[8]; unsigned short rk[8];
#pragma unroll
    for (int k = 0; k < 2; ++k) {
        int e = e0 + k * 4096 + t * 4;
        int4 sv, dv;
        if (e + 3 < N_EDGES) {                 // fast path: 16B aligned vector loads
            sv = *(const int4*)&ei[e];
            dv = *(const int4*)&ei[N_EDGES + e];
        } else {
            int* sp = (int*)&sv; int* dp = (int*)&dv;
#pragma unroll
            for (int j = 0; j < 4; ++j) {
                int ee = e + j;
                if (ee < N_EDGES)      { sp[j] = ei[ee]; dp[j] = ei[N_EDGES + ee]; }
                else if (ee < ET)      { sp[j] = dp[j] = ee - N_EDGES; }
                else                   { sp[j] = dp[j] = -1; }
            }
        }
        const int* sp = (const int*)&sv; const int* dp = (const int*)&dv;
#pragma unroll
        for (int j = 0; j < 4; ++j) {
            int i = k * 4 + j;
            int d = dp[j];
            if (d >= 0) {
                int b = d >> BSHIFT;
                bk[i] = (short)b;
                rk[i] = (unsigned short)atomicAdd(&lc[b], 1);
                u[i] = (unsigned)sp[j] | ((unsigned)d << 16);
            } else bk[i] = -1;
        }
    }
    __syncthreads();
    if (t < NBUCK)
        lbase[t] = lc[t] ? (t * CAP + atomicAdd(&bcur[t], lc[t])) : 0;
    __syncthreads();
#pragma unroll
    for (int i = 0; i < 8; ++i)
        if (bk[i] >= 0) rec[lbase[bk[i]] + rk[i]] = u[i];
}

// ---------------- scan helper (8 waves) ----------------
__device__ __forceinline__ int block_incl_scan(int v, int t, int* wsum) {
    int lane = t & 63, wave = t >> 6;
#pragma unroll
    for (int off = 1; off < 64; off <<= 1) {
        int n = __shfl_up(v, off);
        if (lane >= off) v += n;
    }
    if (lane == 63) wsum[wave] = v;
    __syncthreads();
    int add = 0;
    for (int w = 0; w < wave; ++w) add += wsum[w];
    return v + add;
}

// ---------------- per-bucket CSR build + edge-weight precompute ----------------
__global__ __launch_bounds__(512) void csrb_kernel(const unsigned* __restrict__ rec,
                                                   const int* __restrict__ bcur,
                                                   const float* __restrict__ as,
                                                   const float* __restrict__ ad,
                                                   int* __restrict__ offsets,
                                                   int* __restrict__ counts,
                                                   unsigned* __restrict__ wcsr) {
    __shared__ unsigned lrec[CAP];            // 18.9 KB
    __shared__ int lcnt[BNODES], loff[BNODES], lcur[BNODES];
    __shared__ float adl[BNODES];
    __shared__ int wsum[8];
    int t = threadIdx.x;
    int b = blockIdx.x;
    int n0 = b << BSHIFT;
    int r0 = b * CAP;
    int cnt_b = bcur[b];
    if (t < BNODES) {
        lcnt[t] = 0; lcur[t] = 0;
        adl[t] = (n0 + t < N_NODES) ? ad[n0 + t] : 0.f;
    }
    for (int i = t; i < cnt_b; i += 512) lrec[i] = rec[r0 + i];
    __syncthreads();
    for (int i = t; i < cnt_b; i += 512)
        atomicAdd(&lcnt[(lrec[i] >> 16) & (BNODES - 1)], 1);
    __syncthreads();
    int v = (t < BNODES) ? lcnt[t] : 0;
    int incl = block_incl_scan(v, t, wsum);
    if (t < BNODES) {
        loff[t] = incl - v;
        if (n0 + t < N_NODES) { counts[n0 + t] = v; offsets[n0 + t] = r0 + incl - v; }
    }
    __syncthreads();
    for (int i = t; i < cnt_b; i += 512) {
        unsigned u = lrec[i];
        int dl = (u >> 16) & (BNODES - 1);
        int s = u & 0xFFFFu;
        float ev = as[s] + adl[dl];
        ev = ev > 0.f ? ev : SLOPE * ev;
        float w = __expf(ev);
        int pos = atomicAdd(&lcur[dl], 1);
        wcsr[r0 + loff[dl] + pos] =
            (unsigned)s | ((unsigned)__half_as_ushort(__float2half(w)) << 16);
    }
}

// ---------------- gather: wave/dst, 8 streams x 8 lanes, fdot2 pairs, wave-uniform tiering ----------------
#define H2(x_) __builtin_bit_cast(half2v, (x_))
#define CONS2(uA_, hA_, uB_, hB_)                                              \
    {                                                                          \
        unsigned wp_ = __builtin_amdgcn_perm((uB_), (uA_), 0x07060302u);       \
        half2v wh_ = H2(wp_);                                                  \
        unsigned lo_, hi_;                                                     \
        lo_ = __builtin_amdgcn_perm((hB_).x, (hA_).x, 0x05040100u);            \
        hi_ = __builtin_amdgcn_perm((hB_).x, (hA_).x, 0x07060302u);            \
        a0 = __builtin_amdgcn_fdot2(H2(lo_), wh_, a0, false);                  \
        a1 = __builtin_amdgcn_fdot2(H2(hi_), wh_, a1, false);                  \
        lo_ = __builtin_amdgcn_perm((hB_).y, (hA_).y, 0x05040100u);            \
        hi_ = __builtin_amdgcn_perm((hB_).y, (hA_).y, 0x07060302u);            \
        a2 = __builtin_amdgcn_fdot2(H2(lo_), wh_, a2, false);                  \
        a3 = __builtin_amdgcn_fdot2(H2(hi_), wh_, a3, false);                  \
        lo_ = __builtin_amdgcn_perm((hB_).z, (hA_).z, 0x05040100u);            \
        hi_ = __builtin_amdgcn_perm((hB_).z, (hA_).z, 0x07060302u);            \
        a4 = __builtin_amdgcn_fdot2(H2(lo_), wh_, a4, false);                  \
        a5 = __builtin_amdgcn_fdot2(H2(hi_), wh_, a5, false);                  \
        lo_ = __builtin_amdgcn_perm((hB_).w, (hA_).w, 0x05040100u);            \
        hi_ = __builtin_amdgcn_perm((hB_).w, (hA_).w, 0x07060302u);            \
        a6 = __builtin_amdgcn_fdot2(H2(lo_), wh_, a6, false);                  \
        a7 = __builtin_amdgcn_fdot2(H2(hi_), wh_, a7, false);                  \
        ws = __builtin_amdgcn_fdot2(ones_, wh_, ws, false);                    \
    }

__global__ __launch_bounds__(256) void gather_kernel(const unsigned* __restrict__ wcsr,
                                                     const int* __restrict__ offsets,
                                                     const int* __restrict__ counts,
                                                     const __half* __restrict__ xp,
                                                     const float* __restrict__ bias,
                                                     float* __restrict__ out) {
    __shared__ unsigned stage[4][64];
    int wave = threadIdx.x >> 6, lane = threadIdx.x & 63;
    int d = blockIdx.x * 4 + wave;
    if (d >= N_NODES) return;
    int start = offsets[d], cnt = counts[d];
    int o = lane >> 3, f8 = lane & 7;          // stream o, feature-oct f8
    const uint4* xp4 = (const uint4*)xp;       // 16 B = 8 halves
    const half2v ones_ = { (_Float16)1.f, (_Float16)1.f };
    float a0 = 0.f, a1 = 0.f, a2 = 0.f, a3 = 0.f;
    float a4 = 0.f, a5 = 0.f, a6 = 0.f, a7 = 0.f;
    float ws = 0.f;

    for (int jb = 0; jb < cnt; jb += 64) {
        int iters = min(cnt - jb, 64);
        stage[wave][lane] = (lane < iters) ? wcsr[start + jb + lane] : 0u;
        // records 0..31 live in streams' first 4 slots (u0..u3)
        unsigned u0 = stage[wave][o];
        unsigned u1 = stage[wave][o + 8];
        unsigned u2 = stage[wave][o + 16];
        unsigned u3 = stage[wave][o + 24];
        uint4 h0 = xp4[(u0 & 0xFFFFu) * 8 + f8];
        uint4 h1 = xp4[(u1 & 0xFFFFu) * 8 + f8];
        uint4 h2 = xp4[(u2 & 0xFFFFu) * 8 + f8];
        uint4 h3 = xp4[(u3 & 0xFFFFu) * 8 + f8];
        bool second = iters > 32;              // wave-uniform branch
        unsigned u4, u5, u6, u7;
        uint4 h4, h5, h6, h7;
        if (second) {                          // issue second-half loads early
            u4 = stage[wave][o + 32];
            u5 = stage[wave][o + 40];
            u6 = stage[wave][o + 48];
            u7 = stage[wave][o + 56];
            h4 = xp4[(u4 & 0xFFFFu) * 8 + f8];
            h5 = xp4[(u5 & 0xFFFFu) * 8 + f8];
            h6 = xp4[(u6 & 0xFFFFu) * 8 + f8];
            h7 = xp4[(u7 & 0xFFFFu) * 8 + f8];
        }
        CONS2(u0, h0, u1, h1);
        CONS2(u2, h2, u3, h3);
        if (second) {
            CONS2(u4, h4, u5, h5);
            CONS2(u6, h6, u7, h7);
        }
    }
    // reduce across the 8 streams (lanes differing in bits 3..5)
#pragma unroll
    for (int off = 8; off < 64; off <<= 1) {
        a0 += __shfl_xor(a0, off);
        a1 += __shfl_xor(a1, off);
        a2 += __shfl_xor(a2, off);
        a3 += __shfl_xor(a3, off);
        a4 += __shfl_xor(a4, off);
        a5 += __shfl_xor(a5, off);
        a6 += __shfl_xor(a6, off);
        a7 += __shfl_xor(a7, off);
        ws += __shfl_xor(ws, off);
    }
    if (o == 0) {
        float inv = 1.f / ws;
        float4 b0 = ((const float4*)bias)[f8 * 2];
        float4 b1 = ((const float4*)bias)[f8 * 2 + 1];
        float4 o0, o1;
        o0.x = fmaf(a0, inv, b0.x); o0.y = fmaf(a1, inv, b0.y);
        o0.z = fmaf(a2, inv, b0.z); o0.w = fmaf(a3, inv, b0.w);
        o1.x = fmaf(a4, inv, b1.x); o1.y = fmaf(a5, inv, b1.y);
        o1.z = fmaf(a6, inv, b1.z); o1.w = fmaf(a7, inv, b1.w);
        o0.x = o0.x > 0.f ? o0.x : 0.f;
        o0.y = o0.y > 0.f ? o0.y : 0.f;
        o0.z = o0.z > 0.f ? o0.z : 0.f;
        o0.w = o0.w > 0.f ? o0.w : 0.f;
        o1.x = o1.x > 0.f ? o1.x : 0.f;
        o1.y = o1.y > 0.f ? o1.y : 0.f;
        o1.z = o1.z > 0.f ? o1.z : 0.f;
        o1.w = o1.w > 0.f ? o1.w : 0.f;
        ((float4*)out)[(size_t)d * 16 + f8 * 2]     = o0;
        ((float4*)out)[(size_t)d * 16 + f8 * 2 + 1] = o1;
    }
}

extern "C" void kernel_launch(void* const* d_in, const int* in_sizes, int n_in,
                              void* d_out, int out_size, void* d_ws, size_t ws_size,
                              hipStream_t stream) {
    const float* x     = (const float*)d_in[0];
    const float* W     = (const float*)d_in[1];
    const float* a_src = (const float*)d_in[2];
    const float* a_dst = (const float*)d_in[3];
    const float* bias  = (const float*)d_in[4];
    const int*   ei    = (const int*)d_in[5];
    float* out = (float*)d_out;

    _Float16* xph   = (_Float16*)d_ws;                        // N*64 fp16
    float*  as      = (float*)(xph + (size_t)N_NODES * F_OUT);
    float*  ad      = as + N_NODES;
    int*    counts  = (int*)(ad + N_NODES);                   // N
    int*    offsets = counts + N_NODES;                       // N
    int*    bcur    = offsets + N_NODES;                      // NBUCK
    unsigned* rec   = (unsigned*)(bcur + NBUCK + 64);         // NBUCK*CAP u32
    unsigned* wcsr  = rec + (size_t)NBUCK * CAP;              // NBUCK*CAP u32

    gemm_kernel<<<(N_NODES + 63) / 64, 256, 0, stream>>>(
        (const float4*)x, W, a_src, a_dst, xph, as, ad, bcur);
    part_kernel<<<PBLOCKS, 1024, 0, stream>>>(ei, bcur, rec);
    csrb_kernel<<<NBUCK, 512, 0, stream>>>(rec, bcur, as, ad, offsets, counts, wcsr);
    gather_kernel<<<(N_NODES + 3) / 4, 256, 0, stream>>>(wcsr, offsets, counts,
                                                         (const __half*)xph, bias, out);
}